// Round 8
// baseline (497.457 us; speedup 1.0000x reference)
//
#include <hip/hip_runtime.h>

namespace {

constexpr int kNIn = 128;
constexpr int kNRec = 128;
constexpr int BR = 128;             // rows per block (8 per thread)
constexpr int KC = 16;              // k-chunk staged in LDS
constexpr int NCH = kNIn / KC;      // 8 chunks
constexpr int XP = 4;               // sxT/szT row pad: stride 132 floats
                                    // -> staging write banks (4r+srow)%32,
                                    //    2-way max (free); 16B align kept.

typedef float vfloat4 __attribute__((ext_vector_type(4)));

__device__ __forceinline__ float fcomp(const float4 f, int i) {
  switch (i & 3) {
    case 0: return f.x;
    case 1: return f.y;
    case 2: return f.z;
    default: return f.w;
  }
}

__device__ __forceinline__ void nt_store4(float* p, float a, float b, float c,
                                          float d) {
  vfloat4 val = {a, b, c, d};
  __builtin_nontemporal_store(val, reinterpret_cast<vfloat4*>(p));
}

// Round-7: R6 counters showed LDS-read-BW-bound (25.2 MB/CU ~ 123us of the
// 202us wall; VALUBusy 39% == FMA/LDS cycle ratio). This version doubles
// the thread tile to 8 rows x 8 cols (BR=128): per k, 8 ds_read_b128
// (4 weights + 2 x + 2 z) feed 128 FMAs -> 1.0 B/FMA (was 1.5), LDS
// volume 16.8 MB/CU (~82us). Also pads sxT/szT stride to 132 floats to
// kill the 4-way staging-write bank conflict R6 measured (3.15M cycles).
// Structure otherwise identical to R6: barrier-pinned LDS staging (the
// only pipeline this compiler preserves), launch_bounds(256,4) (the only
// bound that never spilled: R4/R5 caps 64/85 both spilled), NT stores
// (R2: cached stores add RFO fetch at zero benefit).
// Per-element FMA order ch->kq->kk, a-then-b: unchanged -> bit-identical.
__global__ __launch_bounds__(256, 4) void lif_fused(
    const float* __restrict__ x, const float* __restrict__ z,
    const float* __restrict__ v, const float* __restrict__ t,
    const float* __restrict__ w_in, const float* __restrict__ w_rec,
    float* __restrict__ out, int batch) {
  __shared__ float swi[KC][kNRec];       // 8 KB
  __shared__ float swr[KC][kNRec];       // 8 KB
  __shared__ float sxT[KC][BR + XP];     // 8.25 KB, transposed [k][row]
  __shared__ float szT[KC][BR + XP];     // 8.25 KB

  const int tid = threadIdx.x;
  const int tc = tid & 15;          // 16 col groups x (4 + 4) cols
  const int tr = tid >> 4;          // 16 row groups x 8 rows = 128 rows
  const int brow = blockIdx.x * BR;
  const int row0 = brow + tr * 8;
  const int c0 = tc * 4;

  // staging coords: thread covers row srow, k-octet sq (8 k values)
  const int srow = tid >> 1;        // 0..127
  const int sq = tid & 1;           // 0..1

  float acc[8][8];
#pragma unroll
  for (int i = 0; i < 8; ++i)
#pragma unroll
    for (int c = 0; c < 8; ++c) acc[i][c] = 0.0f;

  float4* swi4 = reinterpret_cast<float4*>(&swi[0][0]);
  float4* swr4 = reinterpret_cast<float4*>(&swr[0][0]);

  for (int ch = 0; ch < NCH; ++ch) {
    // ---- stage weights (KC x 128 each) + x/z tiles (BR x KC each) ----
    // Global loads issued before the chunk-open barrier (barrier-pinned
    // async-stage: scheduler cannot sink these into the FMA loop).
    const float4* gwi =
        reinterpret_cast<const float4*>(w_in + (size_t)ch * KC * kNRec);
    const float4* gwr =
        reinterpret_cast<const float4*>(w_rec + (size_t)ch * KC * kNRec);
    float4 wa[2], wb[2];
#pragma unroll
    for (int j = 0; j < 2; ++j) {
      wa[j] = gwi[tid + 256 * j];
      wb[j] = gwr[tid + 256 * j];
    }
    float4 xv[2], zv[2];
#pragma unroll
    for (int j = 0; j < 2; ++j) {
      xv[j] = *reinterpret_cast<const float4*>(
          x + (size_t)(brow + srow) * kNIn + ch * KC + sq * 8 + 4 * j);
      zv[j] = *reinterpret_cast<const float4*>(
          z + (size_t)(brow + srow) * kNRec + ch * KC + sq * 8 + 4 * j);
    }

    if (ch) __syncthreads();  // prior chunk's readers must be done
#pragma unroll
    for (int j = 0; j < 2; ++j) {
      swi4[tid + 256 * j] = wa[j];
      swr4[tid + 256 * j] = wb[j];
    }
#pragma unroll
    for (int j = 0; j < 8; ++j) {   // transpose into [k][row]
      sxT[sq * 8 + j][srow] = fcomp(xv[j >> 2], j & 3);
      szT[sq * 8 + j][srow] = fcomp(zv[j >> 2], j & 3);
    }
    __syncthreads();

    // ---- compute: pure LDS operands, 8 reads -> 128 FMAs per k ----
#pragma unroll
    for (int kq = 0; kq < KC / 4; ++kq) {
#pragma unroll
      for (int kk = 0; kk < 4; ++kk) {
        const int k = kq * 4 + kk;
        const float4 wi0 = *reinterpret_cast<const float4*>(&swi[k][c0]);
        const float4 wi1 = *reinterpret_cast<const float4*>(&swi[k][c0 + 64]);
        const float4 wr0 = *reinterpret_cast<const float4*>(&swr[k][c0]);
        const float4 wr1 = *reinterpret_cast<const float4*>(&swr[k][c0 + 64]);
        float4 xkh[2], zkh[2];
        xkh[0] = *reinterpret_cast<const float4*>(&sxT[k][tr * 8]);
        xkh[1] = *reinterpret_cast<const float4*>(&sxT[k][tr * 8 + 4]);
        zkh[0] = *reinterpret_cast<const float4*>(&szT[k][tr * 8]);
        zkh[1] = *reinterpret_cast<const float4*>(&szT[k][tr * 8 + 4]);
#pragma unroll
        for (int ih = 0; ih < 2; ++ih) {
          const float4 xk = xkh[ih];
          const float4 zk = zkh[ih];
#pragma unroll
          for (int ii = 0; ii < 4; ++ii) {
            const int i = ih * 4 + ii;
            const float a = fcomp(xk, ii);
            const float b = fcomp(zk, ii);
            acc[i][0] = __fmaf_rn(a, wi0.x, acc[i][0]);
            acc[i][1] = __fmaf_rn(a, wi0.y, acc[i][1]);
            acc[i][2] = __fmaf_rn(a, wi0.z, acc[i][2]);
            acc[i][3] = __fmaf_rn(a, wi0.w, acc[i][3]);
            acc[i][4] = __fmaf_rn(a, wi1.x, acc[i][4]);
            acc[i][5] = __fmaf_rn(a, wi1.y, acc[i][5]);
            acc[i][6] = __fmaf_rn(a, wi1.z, acc[i][6]);
            acc[i][7] = __fmaf_rn(a, wi1.w, acc[i][7]);
            acc[i][0] = __fmaf_rn(b, wr0.x, acc[i][0]);
            acc[i][1] = __fmaf_rn(b, wr0.y, acc[i][1]);
            acc[i][2] = __fmaf_rn(b, wr0.z, acc[i][2]);
            acc[i][3] = __fmaf_rn(b, wr0.w, acc[i][3]);
            acc[i][4] = __fmaf_rn(b, wr1.x, acc[i][4]);
            acc[i][5] = __fmaf_rn(b, wr1.y, acc[i][5]);
            acc[i][6] = __fmaf_rn(b, wr1.z, acc[i][6]);
            acc[i][7] = __fmaf_rn(b, wr1.w, acc[i][7]);
          }
        }
      }
    }
  }

  // decay**e table, e in [0,7]: t in [0,4] -> exponent new_t+1 <= 6.
  float ptab[8];
  {
    double d = 1.0;
    const double base = (double)0.95f;
#pragma unroll
    for (int j = 0; j < 8; ++j) {
      ptab[j] = (float)d;
      d *= base;
    }
  }

  const size_t BN = (size_t)batch * kNRec;
  float* __restrict__ out_z = out;
  float* __restrict__ out_v = out + BN;
  float* __restrict__ out_t = out + 2 * BN;

#pragma unroll
  for (int i = 0; i < 8; ++i) {
#pragma unroll
    for (int hlf = 0; hlf < 2; ++hlf) {
      const size_t off = (size_t)(row0 + i) * kNRec + c0 + hlf * 64;
      const vfloat4 vv =
          __builtin_nontemporal_load(reinterpret_cast<const vfloat4*>(v + off));
      const vfloat4 tt =
          __builtin_nontemporal_load(reinterpret_cast<const vfloat4*>(t + off));
      const vfloat4 zz = *reinterpret_cast<const vfloat4*>(z + off);
      float oz[4], ov[4], ot[4];
#pragma unroll
      for (int c = 0; c < 4; ++c) {
        const float s = acc[i][hlf * 4 + c];           // i_in
        const bool h = (s != 0.0f);                    // h = (i_in != 0)
        const float tcur = tt[c];
        const float ntv = h ? tcur : __fadd_rn(tcur, 1.0f);  // new_t pre-reset
        const float vcur = vv[c];
        const float zcur = zz[c];
        // new_v = v * (1 - z)
        float nv = __fmul_rn(vcur, __fsub_rn(1.0f, zcur));
        // clamp below -1: new_v -= (1 - (v > -1)) * (v + 1)
        const float lp = (vcur > -1.0f) ? 1.0f : 0.0f;
        nv = __fsub_rn(nv,
                       __fmul_rn(__fsub_rn(1.0f, lp), __fadd_rn(vcur, 1.0f)));
        // new_v *= decay ** (h * (new_t + 1))
        int ei = h ? (int)__fadd_rn(ntv, 1.0f) : 0;
        ei = ei < 0 ? 0 : (ei > 7 ? 7 : ei);
        nv = __fmul_rn(nv, ptab[ei]);
        // new_v += i_in
        nv = __fadd_rn(nv, s);
        // new_z = spike((new_v - THR)/THR)  <=>  new_v > THR
        oz[c] = (nv > 0.4f) ? 1.0f : 0.0f;
        ov[c] = nv;
        ot[c] = h ? 0.0f : ntv;  // new_t *= (h != 1)
      }
      nt_store4(out_z + off, oz[0], oz[1], oz[2], oz[3]);
      nt_store4(out_v + off, ov[0], ov[1], ov[2], ov[3]);
      nt_store4(out_t + off, ot[0], ot[1], ot[2], ot[3]);
    }
  }
}

}  // namespace

extern "C" void kernel_launch(void* const* d_in, const int* in_sizes, int n_in,
                              void* d_out, int out_size, void* d_ws, size_t ws_size,
                              hipStream_t stream) {
  const float* x = (const float*)d_in[0];
  const float* z = (const float*)d_in[1];
  const float* v = (const float*)d_in[2];
  const float* t = (const float*)d_in[3];
  const float* w_in = (const float*)d_in[4];
  const float* w_rec = (const float*)d_in[5];
  float* out = (float*)d_out;

  const int batch = in_sizes[0] / kNIn;  // 131072
  const int blocks = batch / BR;         // 1024 blocks of 128 rows
  lif_fused<<<blocks, 256, 0, stream>>>(x, z, v, t, w_in, w_rec, out, batch);
}

// Round 9
// 491.962 us; speedup vs baseline: 1.0112x; 1.0112x over previous
//
#include <hip/hip_runtime.h>

namespace {

constexpr int kNIn = 128;
constexpr int kNRec = 128;
constexpr int BR = 128;             // rows per block (8 per thread)
constexpr int KC = 16;              // k-chunk staged in LDS
constexpr int NCH = kNIn / KC;      // 8 chunks
constexpr int XP = 4;               // sxT/szT row pad: stride 132 floats
                                    // -> staging write banks (4r+srow)%32,
                                    //    2-way max (free); 16B align kept.

typedef float vfloat4 __attribute__((ext_vector_type(4)));

__device__ __forceinline__ float fcomp(const float4 f, int i) {
  switch (i & 3) {
    case 0: return f.x;
    case 1: return f.y;
    case 2: return f.z;
    default: return f.w;
  }
}

__device__ __forceinline__ void nt_store4(float* p, float a, float b, float c,
                                          float d) {
  vfloat4 val = {a, b, c, d};
  __builtin_nontemporal_store(val, reinterpret_cast<vfloat4*>(p));
}

// Round-9: R8 (8x8 tile) regressed 202->242us with VGPR_Count=64: the
// backend's occupancy heuristic targets 8 waves/EU (<=64 VGPR) regardless
// of launch_bounds' min=4, and fit the 64-float acc tile by AGPR
// ping-pong (no scratch: WRITE stayed 438MB), tripling VALU work.
// Cross-round law: R0:56, R2:64(sank pipeline), R3/R4/R5:spill, R6:48,
// R8:64(AGPR shuffle) -- the allocator NEVER exceeds 64 unless the
// occupancy TARGET itself is lowered. amdgpu_waves_per_eu(4,4) pins the
// target to 4 waves/EU: budget 128 VGPR, acc[8][8] fits in arch VGPRs.
// 4 waves/EU = 16 waves/CU is what R6 effectively achieved (45% occ), so
// no realized TLP is lost; LDS reads stay at 8 ds_read_b128 per 128 FMAs
// (1.0 B/FMA, 16.8 MB/CU ~ 82us vs R6's 123us).
// Structure otherwise R8 == R6-with-bigger-tile: barrier-pinned LDS
// staging (the only pipeline this compiler preserves), transposed+padded
// x/z tiles (R6 measured 3.15M cycles of 4-way staging-write conflicts
// without the pad), NT stores (R2: cached stores add RFO fetch, zero
// benefit). Per-element FMA order ch->kq->kk, a-then-b: unchanged ->
// bit-identical output (absmax 0.0078125 all rounds).
__global__ __launch_bounds__(256)
__attribute__((amdgpu_waves_per_eu(4, 4))) void lif_fused(
    const float* __restrict__ x, const float* __restrict__ z,
    const float* __restrict__ v, const float* __restrict__ t,
    const float* __restrict__ w_in, const float* __restrict__ w_rec,
    float* __restrict__ out, int batch) {
  __shared__ float swi[KC][kNRec];       // 8 KB
  __shared__ float swr[KC][kNRec];       // 8 KB
  __shared__ float sxT[KC][BR + XP];     // 8.25 KB, transposed [k][row]
  __shared__ float szT[KC][BR + XP];     // 8.25 KB

  const int tid = threadIdx.x;
  const int tc = tid & 15;          // 16 col groups x (4 + 4) cols
  const int tr = tid >> 4;          // 16 row groups x 8 rows = 128 rows
  const int brow = blockIdx.x * BR;
  const int row0 = brow + tr * 8;
  const int c0 = tc * 4;

  // staging coords: thread covers row srow, k-octet sq (8 k values)
  const int srow = tid >> 1;        // 0..127
  const int sq = tid & 1;           // 0..1

  float acc[8][8];
#pragma unroll
  for (int i = 0; i < 8; ++i)
#pragma unroll
    for (int c = 0; c < 8; ++c) acc[i][c] = 0.0f;

  float4* swi4 = reinterpret_cast<float4*>(&swi[0][0]);
  float4* swr4 = reinterpret_cast<float4*>(&swr[0][0]);

  for (int ch = 0; ch < NCH; ++ch) {
    // ---- stage weights (KC x 128 each) + x/z tiles (BR x KC each) ----
    // Global loads issued before the chunk-open barrier (barrier-pinned
    // async-stage: scheduler cannot sink these into the FMA loop).
    const float4* gwi =
        reinterpret_cast<const float4*>(w_in + (size_t)ch * KC * kNRec);
    const float4* gwr =
        reinterpret_cast<const float4*>(w_rec + (size_t)ch * KC * kNRec);
    float4 wa[2], wb[2];
#pragma unroll
    for (int j = 0; j < 2; ++j) {
      wa[j] = gwi[tid + 256 * j];
      wb[j] = gwr[tid + 256 * j];
    }
    float4 xv[2], zv[2];
#pragma unroll
    for (int j = 0; j < 2; ++j) {
      xv[j] = *reinterpret_cast<const float4*>(
          x + (size_t)(brow + srow) * kNIn + ch * KC + sq * 8 + 4 * j);
      zv[j] = *reinterpret_cast<const float4*>(
          z + (size_t)(brow + srow) * kNRec + ch * KC + sq * 8 + 4 * j);
    }

    if (ch) __syncthreads();  // prior chunk's readers must be done
#pragma unroll
    for (int j = 0; j < 2; ++j) {
      swi4[tid + 256 * j] = wa[j];
      swr4[tid + 256 * j] = wb[j];
    }
#pragma unroll
    for (int j = 0; j < 8; ++j) {   // transpose into [k][row]
      sxT[sq * 8 + j][srow] = fcomp(xv[j >> 2], j & 3);
      szT[sq * 8 + j][srow] = fcomp(zv[j >> 2], j & 3);
    }
    __syncthreads();

    // ---- compute: pure LDS operands, 8 reads -> 128 FMAs per k ----
#pragma unroll
    for (int kq = 0; kq < KC / 4; ++kq) {
#pragma unroll
      for (int kk = 0; kk < 4; ++kk) {
        const int k = kq * 4 + kk;
        const float4 wi0 = *reinterpret_cast<const float4*>(&swi[k][c0]);
        const float4 wi1 = *reinterpret_cast<const float4*>(&swi[k][c0 + 64]);
        const float4 wr0 = *reinterpret_cast<const float4*>(&swr[k][c0]);
        const float4 wr1 = *reinterpret_cast<const float4*>(&swr[k][c0 + 64]);
        float4 xkh[2], zkh[2];
        xkh[0] = *reinterpret_cast<const float4*>(&sxT[k][tr * 8]);
        xkh[1] = *reinterpret_cast<const float4*>(&sxT[k][tr * 8 + 4]);
        zkh[0] = *reinterpret_cast<const float4*>(&szT[k][tr * 8]);
        zkh[1] = *reinterpret_cast<const float4*>(&szT[k][tr * 8 + 4]);
#pragma unroll
        for (int ih = 0; ih < 2; ++ih) {
          const float4 xk = xkh[ih];
          const float4 zk = zkh[ih];
#pragma unroll
          for (int ii = 0; ii < 4; ++ii) {
            const int i = ih * 4 + ii;
            const float a = fcomp(xk, ii);
            const float b = fcomp(zk, ii);
            acc[i][0] = __fmaf_rn(a, wi0.x, acc[i][0]);
            acc[i][1] = __fmaf_rn(a, wi0.y, acc[i][1]);
            acc[i][2] = __fmaf_rn(a, wi0.z, acc[i][2]);
            acc[i][3] = __fmaf_rn(a, wi0.w, acc[i][3]);
            acc[i][4] = __fmaf_rn(a, wi1.x, acc[i][4]);
            acc[i][5] = __fmaf_rn(a, wi1.y, acc[i][5]);
            acc[i][6] = __fmaf_rn(a, wi1.z, acc[i][6]);
            acc[i][7] = __fmaf_rn(a, wi1.w, acc[i][7]);
            acc[i][0] = __fmaf_rn(b, wr0.x, acc[i][0]);
            acc[i][1] = __fmaf_rn(b, wr0.y, acc[i][1]);
            acc[i][2] = __fmaf_rn(b, wr0.z, acc[i][2]);
            acc[i][3] = __fmaf_rn(b, wr0.w, acc[i][3]);
            acc[i][4] = __fmaf_rn(b, wr1.x, acc[i][4]);
            acc[i][5] = __fmaf_rn(b, wr1.y, acc[i][5]);
            acc[i][6] = __fmaf_rn(b, wr1.z, acc[i][6]);
            acc[i][7] = __fmaf_rn(b, wr1.w, acc[i][7]);
          }
        }
      }
    }
  }

  // decay**e table, e in [0,7]: t in [0,4] -> exponent new_t+1 <= 6.
  float ptab[8];
  {
    double d = 1.0;
    const double base = (double)0.95f;
#pragma unroll
    for (int j = 0; j < 8; ++j) {
      ptab[j] = (float)d;
      d *= base;
    }
  }

  const size_t BN = (size_t)batch * kNRec;
  float* __restrict__ out_z = out;
  float* __restrict__ out_v = out + BN;
  float* __restrict__ out_t = out + 2 * BN;

#pragma unroll
  for (int i = 0; i < 8; ++i) {
#pragma unroll
    for (int hlf = 0; hlf < 2; ++hlf) {
      const size_t off = (size_t)(row0 + i) * kNRec + c0 + hlf * 64;
      const vfloat4 vv =
          __builtin_nontemporal_load(reinterpret_cast<const vfloat4*>(v + off));
      const vfloat4 tt =
          __builtin_nontemporal_load(reinterpret_cast<const vfloat4*>(t + off));
      const vfloat4 zz = *reinterpret_cast<const vfloat4*>(z + off);
      float oz[4], ov[4], ot[4];
#pragma unroll
      for (int c = 0; c < 4; ++c) {
        const float s = acc[i][hlf * 4 + c];           // i_in
        const bool h = (s != 0.0f);                    // h = (i_in != 0)
        const float tcur = tt[c];
        const float ntv = h ? tcur : __fadd_rn(tcur, 1.0f);  // new_t pre-reset
        const float vcur = vv[c];
        const float zcur = zz[c];
        // new_v = v * (1 - z)
        float nv = __fmul_rn(vcur, __fsub_rn(1.0f, zcur));
        // clamp below -1: new_v -= (1 - (v > -1)) * (v + 1)
        const float lp = (vcur > -1.0f) ? 1.0f : 0.0f;
        nv = __fsub_rn(nv,
                       __fmul_rn(__fsub_rn(1.0f, lp), __fadd_rn(vcur, 1.0f)));
        // new_v *= decay ** (h * (new_t + 1))
        int ei = h ? (int)__fadd_rn(ntv, 1.0f) : 0;
        ei = ei < 0 ? 0 : (ei > 7 ? 7 : ei);
        nv = __fmul_rn(nv, ptab[ei]);
        // new_v += i_in
        nv = __fadd_rn(nv, s);
        // new_z = spike((new_v - THR)/THR)  <=>  new_v > THR
        oz[c] = (nv > 0.4f) ? 1.0f : 0.0f;
        ov[c] = nv;
        ot[c] = h ? 0.0f : ntv;  // new_t *= (h != 1)
      }
      nt_store4(out_z + off, oz[0], oz[1], oz[2], oz[3]);
      nt_store4(out_v + off, ov[0], ov[1], ov[2], ov[3]);
      nt_store4(out_t + off, ot[0], ot[1], ot[2], ot[3]);
    }
  }
}

}  // namespace

extern "C" void kernel_launch(void* const* d_in, const int* in_sizes, int n_in,
                              void* d_out, int out_size, void* d_ws, size_t ws_size,
                              hipStream_t stream) {
  const float* x = (const float*)d_in[0];
  const float* z = (const float*)d_in[1];
  const float* v = (const float*)d_in[2];
  const float* t = (const float*)d_in[3];
  const float* w_in = (const float*)d_in[4];
  const float* w_rec = (const float*)d_in[5];
  float* out = (float*)d_out;

  const int batch = in_sizes[0] / kNIn;  // 131072
  const int blocks = batch / BR;         // 1024 blocks of 128 rows
  lif_fused<<<blocks, 256, 0, stream>>>(x, z, v, t, w_in, w_rec, out, batch);
}